// Round 3
// baseline (2328.170 us; speedup 1.0000x reference)
//
#include <hip/hip_runtime.h>
#include <hip/hip_bf16.h>

typedef float f32x4 __attribute__((ext_vector_type(4)));
typedef short bf16x8 __attribute__((ext_vector_type(8)));

#define NB 50000
#define NK 32
#define NH 128
#define NL 64

static __device__ __forceinline__ unsigned short f2bf(float f) {
    unsigned int u = __float_as_uint(f);
    u += 0x7fffu + ((u >> 16) & 1u);
    return (unsigned short)(u >> 16);
}
static __device__ __forceinline__ float bf2f(unsigned short u) {
    return __uint_as_float(((unsigned int)u) << 16);
}
static __device__ __forceinline__ float bflo(unsigned int u) { return __uint_as_float(u << 16); }
static __device__ __forceinline__ float bfhi(unsigned int u) { return __uint_as_float(u & 0xffff0000u); }

__global__ void kl_zero_kernel(float* out) {
    if (threadIdx.x == 0 && blockIdx.x == 0) out[(size_t)NB * NH] = 0.0f;
}

__global__ void __launch_bounds__(256) vibgat_kernel(
    const float* __restrict__ self_feat, const float* __restrict__ neighbor_feat,
    const float* __restrict__ trust_mask, const float* __restrict__ eps,
    const float* __restrict__ pre_g, const float* __restrict__ pre_b,
    const float* __restrict__ W_mu, const float* __restrict__ b_mu,
    const float* __restrict__ W_lv, const float* __restrict__ b_lv,
    const float* __restrict__ post_g, const float* __restrict__ post_b,
    const float* __restrict__ W_q, const float* __restrict__ b_q,
    const float* __restrict__ W_k, const float* __restrict__ b_k,
    const float* __restrict__ W_v, const float* __restrict__ b_v,
    const float* __restrict__ W_o, const float* __restrict__ b_o,
    float* __restrict__ out)
{
    __shared__ unsigned short z_all[4][32 * 64];   // 16KB: per-wave z, swizzled
    __shared__ uint4 WqB[4 * 4 * 64];              // 16KB: W_q B-frag blob [nt][s][lane]
    __shared__ uint4 WkvB[8 * 2 * 64];             // 16KB: W_k|W_v B-frag blob [nt][s][lane]
    __shared__ uint2 WoP[32 * 64];                 // 16KB: W_o packed [c2][h'] (lo=h, hi=h+64)
    __shared__ float2 s_pgb[128];                  // 1KB: (pre_g, pre_b)
    __shared__ float ctxl[4][64];                  // 1KB
    __shared__ float klw[4];

    const int t = threadIdx.x;
    const int w = t >> 6, l = t & 63, g = l >> 4, li = l & 15;

    // ---- one-time LDS staging ----
    if (t < 128) s_pgb[t] = make_float2(pre_g[t], pre_b[t]);
    for (int e = t; e < 1024; e += 256) {          // WqB: frag(nt,s,lane)
        int nt = e >> 8, s = (e >> 6) & 3, ln = e & 63;
        int gg = ln >> 4, ll = ln & 15, c = ll + 16 * nt;
        unsigned int p[4];
#pragma unroll
        for (int jp = 0; jp < 4; ++jp) {
            int k = 32 * s + 8 * gg + 2 * jp;
            p[jp] = (unsigned)f2bf(W_q[k * 64 + c]) | ((unsigned)f2bf(W_q[(k + 1) * 64 + c]) << 16);
        }
        WqB[e] = make_uint4(p[0], p[1], p[2], p[3]);
    }
    for (int e = t; e < 1024; e += 256) {          // WkvB: frag(nt,s,lane), nt<4=W_k else W_v
        int nt = e >> 7, s = (e >> 6) & 1, ln = e & 63;
        const float* src = (nt < 4) ? W_k : W_v;
        int gg = ln >> 4, ll = ln & 15, c = ll + 16 * (nt & 3);
        unsigned int p[4];
#pragma unroll
        for (int jp = 0; jp < 4; ++jp) {
            int k = 32 * s + 8 * gg + 2 * jp;
            p[jp] = (unsigned)f2bf(src[k * 64 + c]) | ((unsigned)f2bf(src[(k + 1) * 64 + c]) << 16);
        }
        WkvB[e] = make_uint4(p[0], p[1], p[2], p[3]);
    }
    for (int e = t; e < 2048; e += 256) {          // WoP
        int c2 = e >> 6, h = e & 63;
        unsigned int w0 = (unsigned)f2bf(W_o[(2 * c2) * 128 + h]) | ((unsigned)f2bf(W_o[(2 * c2) * 128 + h + 64]) << 16);
        unsigned int w1 = (unsigned)f2bf(W_o[(2 * c2 + 1) * 128 + h]) | ((unsigned)f2bf(W_o[(2 * c2 + 1) * 128 + h + 64]) << 16);
        WoP[e] = make_uint2(w0, w1);
    }

    // ---- biases in registers (lane-invariant across loop) ----
    float bmu4[4], blv4[4], pg4[4], pb4[4], bq4[4], bv4[4];
#pragma unroll
    for (int nt = 0; nt < 4; ++nt) {
        int c = li + 16 * nt;
        bmu4[nt] = b_mu[c]; blv4[nt] = b_lv[c]; pg4[nt] = post_g[c];
        pb4[nt] = post_b[c]; bq4[nt] = b_q[c];  bv4[nt] = b_v[c];
    }
    float bo0 = b_o[l], bo1 = b_o[64 + l];

    // ---- W_mu|W_lv B-fragments in registers (128 VGPR) ----
    bf16x8 Wml[8][4];
#pragma unroll
    for (int nt = 0; nt < 8; ++nt) {
        const float* src = (nt < 4) ? W_mu : W_lv;
        int c = li + 16 * (nt & 3);
#pragma unroll
        for (int s = 0; s < 4; ++s) {
            int k0 = 32 * s + 8 * g;
            bf16x8 f;
#pragma unroll
            for (int j = 0; j < 8; ++j) f[j] = (short)f2bf(src[(k0 + j) * 64 + c]);
            Wml[nt][s] = f;
        }
    }
    __syncthreads();

    unsigned short* zl = &z_all[w][0];
    const f32x4 zero4 = {0.f, 0.f, 0.f, 0.f};
    const int stride = gridDim.x * 4;
    int bn = blockIdx.x * 4 + w;

    f32x4 nbr[2][4][2];      // prefetched neighbor rows li,16+li cols 32s+8g+4h..
    float epr[2][4][4];      // eps in MFMA-C layout
    float2 sv;               // self[2l..2l+1]
    float trr;               // raw trust[l&31]

    // ---- prologue prefetch ----
    {
        const float* base = neighbor_feat + ((size_t)bn * NK + li) * NH + 8 * g;
#pragma unroll
        for (int t2 = 0; t2 < 2; ++t2)
#pragma unroll
            for (int s = 0; s < 4; ++s)
#pragma unroll
                for (int h = 0; h < 2; ++h)
                    nbr[t2][s][h] = *(const f32x4*)(base + (size_t)t2 * 16 * NH + 32 * s + 4 * h);
        const float* eb = eps + ((size_t)bn * NK + 4 * g) * NL + li;
#pragma unroll
        for (int mt = 0; mt < 2; ++mt)
#pragma unroll
            for (int nt = 0; nt < 4; ++nt)
#pragma unroll
                for (int r = 0; r < 4; ++r)
                    epr[mt][nt][r] = eb[(size_t)(16 * mt + r) * NL + 16 * nt];
        sv = ((const float2*)(self_feat + (size_t)bn * NH))[l];
        trr = trust_mask[(size_t)bn * NK + (l & 31)];
    }

    float kl_acc = 0.f;

    for (; bn < NB; bn += stride) {
        const int nxt = (bn + stride < NB) ? (bn + stride) : bn;

        // ---------- LN -> A-fragments (registers, no LDS) ----------
        float s0 = 0.f, s1 = 0.f;
#pragma unroll
        for (int s = 0; s < 4; ++s)
#pragma unroll
            for (int h = 0; h < 2; ++h) {
                f32x4 v0 = nbr[0][s][h], v1 = nbr[1][s][h];
                s0 += v0[0] + v0[1] + v0[2] + v0[3];
                s1 += v1[0] + v1[1] + v1[2] + v1[3];
            }
        s0 += __shfl_xor(s0, 16); s0 += __shfl_xor(s0, 32);
        s1 += __shfl_xor(s1, 16); s1 += __shfl_xor(s1, 32);
        float m0 = s0 * (1.f / 128.f), m1 = s1 * (1.f / 128.f);
        float q0 = 0.f, q1 = 0.f;
#pragma unroll
        for (int s = 0; s < 4; ++s)
#pragma unroll
            for (int h = 0; h < 2; ++h)
#pragma unroll
                for (int c = 0; c < 4; ++c) {
                    float d0 = nbr[0][s][h][c] - m0; q0 += d0 * d0;
                    float d1 = nbr[1][s][h][c] - m1; q1 += d1 * d1;
                }
        q0 += __shfl_xor(q0, 16); q0 += __shfl_xor(q0, 32);
        q1 += __shfl_xor(q1, 16); q1 += __shfl_xor(q1, 32);
        float inv0 = rsqrtf(q0 * (1.f / 128.f) + 1e-5f);
        float inv1 = rsqrtf(q1 * (1.f / 128.f) + 1e-5f);
        bf16x8 a0[4], a1[4];
#pragma unroll
        for (int s = 0; s < 4; ++s) {
            const float2* gbp = &s_pgb[32 * s + 8 * g];
#pragma unroll
            for (int h = 0; h < 2; ++h)
#pragma unroll
                for (int c = 0; c < 4; ++c) {
                    int j = 4 * h + c;
                    float2 gb = gbp[j];
                    a0[s][j] = (short)f2bf((nbr[0][s][h][c] - m0) * inv0 * gb.x + gb.y);
                    a1[s][j] = (short)f2bf((nbr[1][s][h][c] - m1) * inv1 * gb.x + gb.y);
                }
        }
        // reissue neighbor loads for next node (latency hidden under whole body)
        {
            const float* base = neighbor_feat + ((size_t)nxt * NK + li) * NH + 8 * g;
#pragma unroll
            for (int t2 = 0; t2 < 2; ++t2)
#pragma unroll
                for (int s = 0; s < 4; ++s)
#pragma unroll
                    for (int h = 0; h < 2; ++h)
                        nbr[t2][s][h] = *(const f32x4*)(base + (size_t)t2 * 16 * NH + 32 * s + 4 * h);
        }

        // ---------- P1: GEMM1 mu|lv ----------
        f32x4 acc1[2][8];
#pragma unroll
        for (int mt = 0; mt < 2; ++mt)
#pragma unroll
            for (int nt = 0; nt < 8; ++nt) acc1[mt][nt] = zero4;
#pragma unroll
        for (int s = 0; s < 4; ++s)
#pragma unroll
            for (int nt = 0; nt < 8; ++nt) {
                acc1[0][nt] = __builtin_amdgcn_mfma_f32_16x16x32_bf16(a0[s], Wml[nt][s], acc1[0][nt], 0, 0, 0);
                acc1[1][nt] = __builtin_amdgcn_mfma_f32_16x16x32_bf16(a1[s], Wml[nt][s], acc1[1][nt], 0, 0, 0);
            }

        // q = self @ W_q + b_q (frags from LDS, self broadcast via shfl)
        float q4[4] = {0.f, 0.f, 0.f, 0.f};
#pragma unroll
        for (int s = 0; s < 4; ++s) {
            bf16x8 fq[4];
#pragma unroll
            for (int nt = 0; nt < 4; ++nt)
                fq[nt] = *(const bf16x8*)&WqB[(nt * 4 + s) * 64 + l];
#pragma unroll
            for (int jp = 0; jp < 4; ++jp) {
                int idx = 16 * s + 4 * g + jp;
                float fx = __shfl(sv.x, idx), fy = __shfl(sv.y, idx);
#pragma unroll
                for (int nt = 0; nt < 4; ++nt)
                    q4[nt] += fx * bf2f((unsigned short)fq[nt][2 * jp]) + fy * bf2f((unsigned short)fq[nt][2 * jp + 1]);
            }
        }
#pragma unroll
        for (int nt = 0; nt < 4; ++nt) {
            float p = q4[nt];
            p += __shfl_xor(p, 16); p += __shfl_xor(p, 32);
            q4[nt] = p + bq4[nt];
        }
        // reissue self for next node
        sv = ((const float2*)(self_feat + (size_t)nxt * NH))[l];

        // ---------- P2: reparam + KL + post-LN -> z LDS ----------
#pragma unroll
        for (int mt = 0; mt < 2; ++mt)
#pragma unroll
            for (int nt = 0; nt < 4; ++nt)
#pragma unroll
                for (int r = 0; r < 4; ++r) {
                    float mu = acc1[mt][nt][r] + bmu4[nt];
                    float lv = acc1[mt][nt + 4][r] + blv4[nt];
                    float eh = __expf(0.5f * lv);
                    kl_acc += 1.f + lv - mu * mu - eh * eh;
                    acc1[mt][nt][r] = mu + epr[mt][nt][r] * eh;
                }
#pragma unroll
        for (int mt = 0; mt < 2; ++mt)
#pragma unroll
            for (int r = 0; r < 4; ++r) {
                float s1 = acc1[mt][0][r] + acc1[mt][1][r] + acc1[mt][2][r] + acc1[mt][3][r];
                s1 += __shfl_xor(s1, 1); s1 += __shfl_xor(s1, 2);
                s1 += __shfl_xor(s1, 4); s1 += __shfl_xor(s1, 8);
                float mean = s1 * (1.f / 64.f);
                float s2 = 0.f;
#pragma unroll
                for (int nt = 0; nt < 4; ++nt) { float d = acc1[mt][nt][r] - mean; s2 += d * d; }
                s2 += __shfl_xor(s2, 1); s2 += __shfl_xor(s2, 2);
                s2 += __shfl_xor(s2, 4); s2 += __shfl_xor(s2, 8);
                float inv = rsqrtf(s2 * (1.f / 64.f) + 1e-5f);
                int row = 16 * mt + 4 * g + r;
#pragma unroll
                for (int nt = 0; nt < 4; ++nt) {
                    unsigned short zb = f2bf((acc1[mt][nt][r] - mean) * inv * pg4[nt] + pb4[nt]);
                    *(unsigned short*)((char*)zl + ((row * 128 + (li + 16 * nt) * 2) ^ ((row & 7) << 4))) = zb;
                }
            }
        // reissue eps for next node
        {
            const float* eb = eps + ((size_t)nxt * NK + 4 * g) * NL + li;
#pragma unroll
            for (int mt = 0; mt < 2; ++mt)
#pragma unroll
                for (int nt = 0; nt < 4; ++nt)
#pragma unroll
                    for (int r = 0; r < 4; ++r)
                        epr[mt][nt][r] = eb[(size_t)(16 * mt + r) * NL + 16 * nt];
        }

        // ---------- P3: k|v GEMM + attention ----------
        f32x4 acc2[2][8];
#pragma unroll
        for (int mt = 0; mt < 2; ++mt)
#pragma unroll
            for (int nt = 0; nt < 8; ++nt) acc2[mt][nt] = zero4;
#pragma unroll
        for (int s = 0; s < 2; ++s) {
            bf16x8 A0 = *(const bf16x8*)((const char*)zl + ((li * 128 + s * 64 + g * 16) ^ ((li & 7) << 4)));
            bf16x8 A1 = *(const bf16x8*)((const char*)zl + (((16 + li) * 128 + s * 64 + g * 16) ^ ((li & 7) << 4)));
#pragma unroll
            for (int nt = 0; nt < 8; ++nt) {
                bf16x8 fb = *(const bf16x8*)&WkvB[(nt * 2 + s) * 64 + l];
                acc2[0][nt] = __builtin_amdgcn_mfma_f32_16x16x32_bf16(A0, fb, acc2[0][nt], 0, 0, 0);
                acc2[1][nt] = __builtin_amdgcn_mfma_f32_16x16x32_bf16(A1, fb, acc2[1][nt], 0, 0, 0);
            }
        }
        float trlog = __logf(trr + 1e-6f);
        float att[2][4];
#pragma unroll
        for (int mt = 0; mt < 2; ++mt)
#pragma unroll
            for (int r = 0; r < 4; ++r) {
                float p = q4[0] * acc2[mt][0][r] + q4[1] * acc2[mt][1][r]
                        + q4[2] * acc2[mt][2][r] + q4[3] * acc2[mt][3][r];
                p += __shfl_xor(p, 1); p += __shfl_xor(p, 2);
                p += __shfl_xor(p, 4); p += __shfl_xor(p, 8);
                att[mt][r] = p * 0.125f + __shfl(trlog, 16 * mt + 4 * g + r);
            }
        float m = att[0][0];
#pragma unroll
        for (int mt = 0; mt < 2; ++mt)
#pragma unroll
            for (int r = 0; r < 4; ++r) m = fmaxf(m, att[mt][r]);
        m = fmaxf(m, __shfl_xor(m, 16)); m = fmaxf(m, __shfl_xor(m, 32));
        float den = 0.f;
#pragma unroll
        for (int mt = 0; mt < 2; ++mt)
#pragma unroll
            for (int r = 0; r < 4; ++r) { att[mt][r] = __expf(att[mt][r] - m); den += att[mt][r]; }
        den += __shfl_xor(den, 16); den += __shfl_xor(den, 32);
        float idn = 1.f / den;
#pragma unroll
        for (int nt = 0; nt < 4; ++nt) {
            float cx = 0.f;
#pragma unroll
            for (int mt = 0; mt < 2; ++mt)
#pragma unroll
                for (int r = 0; r < 4; ++r) cx += att[mt][r] * idn * acc2[mt][nt + 4][r];
            cx += __shfl_xor(cx, 16); cx += __shfl_xor(cx, 32);
            if (g == 0) ctxl[w][li + 16 * nt] = cx + bv4[nt];
        }
        // reissue trust for next node
        trr = trust_mask[(size_t)nxt * NK + (l & 31)];

        // ---------- P4: out = ctx @ W_o + b_o ----------
        {
            float o0 = 0.f, o1 = 0.f;
#pragma unroll
            for (int c2 = 0; c2 < 32; ++c2) {
                float2 cc = *(const float2*)&ctxl[w][2 * c2];
                uint2 W2 = WoP[c2 * 64 + l];
                o0 += cc.x * bflo(W2.x) + cc.y * bflo(W2.y);
                o1 += cc.x * bfhi(W2.x) + cc.y * bfhi(W2.y);
            }
            out[(size_t)bn * NH + l] = o0 + bo0;
            out[(size_t)bn * NH + 64 + l] = o1 + bo1;
        }
    }

    // ---------- KL reduction ----------
#pragma unroll
    for (int msk = 1; msk < 64; msk <<= 1) kl_acc += __shfl_xor(kl_acc, msk);
    if (l == 0) klw[w] = kl_acc;
    __syncthreads();
    if (t == 0) {
        float tot = klw[0] + klw[1] + klw[2] + klw[3];
        atomicAdd(out + (size_t)NB * NH, tot * (-0.5f * 0.001f / ((float)NB * NK)));
    }
}

extern "C" void kernel_launch(void* const* d_in, const int* in_sizes, int n_in,
                              void* d_out, int out_size, void* d_ws, size_t ws_size,
                              hipStream_t stream) {
    const float* self_feat     = (const float*)d_in[0];
    const float* neighbor_feat = (const float*)d_in[1];
    const float* trust_mask    = (const float*)d_in[2];
    const float* eps           = (const float*)d_in[3];
    const float* pre_g  = (const float*)d_in[4];
    const float* pre_b  = (const float*)d_in[5];
    const float* W_mu   = (const float*)d_in[6];
    const float* b_mu   = (const float*)d_in[7];
    const float* W_lv   = (const float*)d_in[8];
    const float* b_lv   = (const float*)d_in[9];
    const float* post_g = (const float*)d_in[10];
    const float* post_b = (const float*)d_in[11];
    const float* W_q    = (const float*)d_in[12];
    const float* b_q    = (const float*)d_in[13];
    const float* W_k    = (const float*)d_in[14];
    const float* b_k    = (const float*)d_in[15];
    const float* W_v    = (const float*)d_in[16];
    const float* b_v    = (const float*)d_in[17];
    const float* W_o    = (const float*)d_in[18];
    const float* b_o    = (const float*)d_in[19];
    float* out = (float*)d_out;
    (void)b_k; (void)d_ws; (void)ws_size; (void)in_sizes; (void)n_in; (void)out_size;

    hipLaunchKernelGGL(kl_zero_kernel, dim3(1), dim3(64), 0, stream, out);
    hipLaunchKernelGGL(vibgat_kernel, dim3(512), dim3(256), 0, stream,
                       self_feat, neighbor_feat, trust_mask, eps,
                       pre_g, pre_b, W_mu, b_mu, W_lv, b_lv, post_g, post_b,
                       W_q, b_q, W_k, b_k, W_v, b_v, W_o, b_o, out);
}

// Round 5
// 1082.137 us; speedup vs baseline: 2.1515x; 2.1515x over previous
//
#include <hip/hip_runtime.h>
#include <hip/hip_bf16.h>

typedef float f32x4 __attribute__((ext_vector_type(4)));
typedef short bf16x8 __attribute__((ext_vector_type(8)));

#define NB 50000
#define NK 32
#define NH 128
#define NL 64

static __device__ __forceinline__ unsigned short f2bf(float f) {
    unsigned int u = __float_as_uint(f);
    u += 0x7fffu + ((u >> 16) & 1u);
    return (unsigned short)(u >> 16);
}
static __device__ __forceinline__ float bf2f(unsigned short u) {
    return __uint_as_float(((unsigned int)u) << 16);
}

__global__ void kl_zero_kernel(float* out) {
    if (threadIdx.x == 0 && blockIdx.x == 0) out[(size_t)NB * NH] = 0.0f;
}

// ---------------- K1: q_all = self_feat @ W_q + b_q  (bf16 out to ws) ----------------
__global__ void __launch_bounds__(256) q_kernel(const float* __restrict__ self_feat,
                                                const float* __restrict__ W_q,
                                                const float* __restrict__ b_q,
                                                unsigned short* __restrict__ q_ws)
{
    __shared__ __align__(16) unsigned short A[32 * 128];   // bf16 swizzled, row stride 256B
    const int t = threadIdx.x, w = t >> 6, l = t & 63, g = l >> 4, li = l & 15;

    // B-frags: wave w covers cols li+16w; k = 32s+8g+j
    bf16x8 Bq[4];
#pragma unroll
    for (int s = 0; s < 4; ++s) {
        int k0 = 32 * s + 8 * g, c = li + 16 * w;
        bf16x8 f;
#pragma unroll
        for (int j = 0; j < 8; ++j) f[j] = (short)f2bf(W_q[(k0 + j) * 64 + c]);
        Bq[s] = f;
    }
    const float bq = b_q[li + 16 * w];
    const int n0 = blockIdx.x * 32;

    {   // stage A: row = t>>3, cols (t&7)*16 .. +15
        int row = t >> 3, c0 = (t & 7) * 16;
        float x[16];
        if (n0 + row < NB) {
            const float* src = self_feat + (size_t)(n0 + row) * NH + c0;
#pragma unroll
            for (int i = 0; i < 4; ++i) {
                float4 v4 = ((const float4*)src)[i];
                x[4 * i] = v4.x; x[4 * i + 1] = v4.y; x[4 * i + 2] = v4.z; x[4 * i + 3] = v4.w;
            }
        } else {
#pragma unroll
            for (int i = 0; i < 16; ++i) x[i] = 0.f;
        }
        alignas(16) unsigned short yb[16];
#pragma unroll
        for (int i = 0; i < 16; ++i) yb[i] = f2bf(x[i]);
        int boff = row * 256 + c0 * 2;
        *(int4*)((char*)A + ((boff) ^ ((row & 7) << 4))) = *(int4*)&yb[0];
        *(int4*)((char*)A + ((boff + 16) ^ ((row & 7) << 4))) = *(int4*)&yb[8];
    }
    __syncthreads();

    const f32x4 zero4 = {0.f, 0.f, 0.f, 0.f};
    f32x4 acc[2] = {zero4, zero4};
#pragma unroll
    for (int s = 0; s < 4; ++s) {
        bf16x8 A0 = *(const bf16x8*)((const char*)A + ((li * 256 + s * 64 + g * 16) ^ ((li & 7) << 4)));
        bf16x8 A1 = *(const bf16x8*)((const char*)A + (((16 + li) * 256 + s * 64 + g * 16) ^ ((li & 7) << 4)));
        acc[0] = __builtin_amdgcn_mfma_f32_16x16x32_bf16(A0, Bq[s], acc[0], 0, 0, 0);
        acc[1] = __builtin_amdgcn_mfma_f32_16x16x32_bf16(A1, Bq[s], acc[1], 0, 0, 0);
    }
#pragma unroll
    for (int mt = 0; mt < 2; ++mt)
#pragma unroll
        for (int r = 0; r < 4; ++r) {
            int row = 16 * mt + 4 * g + r;
            if (n0 + row < NB)
                q_ws[(size_t)(n0 + row) * 64 + li + 16 * w] = f2bf(acc[mt][r] + bq);
        }
}

// ---------------- K3: out = ctx @ W_o + b_o  (hi/lo bf16 split of ctx) ----------------
__global__ void __launch_bounds__(256) out_kernel(const float* __restrict__ ctx_ws,
                                                  const float* __restrict__ W_o,
                                                  const float* __restrict__ b_o,
                                                  float* __restrict__ out)
{
    __shared__ __align__(16) unsigned short Ahi[32 * 64];  // swizzled, row stride 128B
    __shared__ __align__(16) unsigned short Alo[32 * 64];
    const int t = threadIdx.x, w = t >> 6, l = t & 63, g = l >> 4, li = l & 15;

    // B-frags: wave w covers cols li+32w+16ntp; k = 32s+8g+j
    bf16x8 Bo[2][2];
#pragma unroll
    for (int ntp = 0; ntp < 2; ++ntp)
#pragma unroll
        for (int s = 0; s < 2; ++s) {
            int k0 = 32 * s + 8 * g, c = li + 32 * w + 16 * ntp;
            bf16x8 f;
#pragma unroll
            for (int j = 0; j < 8; ++j) f[j] = (short)f2bf(W_o[(k0 + j) * 128 + c]);
            Bo[ntp][s] = f;
        }
    const float bo[2] = {b_o[li + 32 * w], b_o[li + 32 * w + 16]};
    const int n0 = blockIdx.x * 32;

    {   // stage A hi/lo: row = t>>3, cols (t&7)*8 .. +7
        int row = t >> 3, c0 = (t & 7) * 8;
        float x[8];
        if (n0 + row < NB) {
            const float* src = ctx_ws + (size_t)(n0 + row) * 64 + c0;
            float4 v0 = ((const float4*)src)[0], v1 = ((const float4*)src)[1];
            x[0] = v0.x; x[1] = v0.y; x[2] = v0.z; x[3] = v0.w;
            x[4] = v1.x; x[5] = v1.y; x[6] = v1.z; x[7] = v1.w;
        } else {
#pragma unroll
            for (int i = 0; i < 8; ++i) x[i] = 0.f;
        }
        alignas(16) unsigned short hb[8], lb[8];
#pragma unroll
        for (int i = 0; i < 8; ++i) {
            unsigned short h = f2bf(x[i]);
            hb[i] = h;
            lb[i] = f2bf(x[i] - bf2f(h));
        }
        int boff = (row * 128 + c0 * 2) ^ ((row & 7) << 4);
        *(int4*)((char*)Ahi + boff) = *(int4*)hb;
        *(int4*)((char*)Alo + boff) = *(int4*)lb;
    }
    __syncthreads();

    const f32x4 zero4 = {0.f, 0.f, 0.f, 0.f};
    f32x4 acc[2][2];
    acc[0][0] = zero4; acc[0][1] = zero4; acc[1][0] = zero4; acc[1][1] = zero4;
#pragma unroll
    for (int s = 0; s < 2; ++s) {
        int o0 = (li * 128 + s * 64 + g * 16) ^ ((li & 7) << 4);
        int o1 = (((16 + li) * 128) + s * 64 + g * 16) ^ (((16 + li) & 7) << 4);
        bf16x8 A0h = *(const bf16x8*)((const char*)Ahi + o0);
        bf16x8 A1h = *(const bf16x8*)((const char*)Ahi + o1);
        bf16x8 A0l = *(const bf16x8*)((const char*)Alo + o0);
        bf16x8 A1l = *(const bf16x8*)((const char*)Alo + o1);
#pragma unroll
        for (int ntp = 0; ntp < 2; ++ntp) {
            acc[0][ntp] = __builtin_amdgcn_mfma_f32_16x16x32_bf16(A0h, Bo[ntp][s], acc[0][ntp], 0, 0, 0);
            acc[0][ntp] = __builtin_amdgcn_mfma_f32_16x16x32_bf16(A0l, Bo[ntp][s], acc[0][ntp], 0, 0, 0);
            acc[1][ntp] = __builtin_amdgcn_mfma_f32_16x16x32_bf16(A1h, Bo[ntp][s], acc[1][ntp], 0, 0, 0);
            acc[1][ntp] = __builtin_amdgcn_mfma_f32_16x16x32_bf16(A1l, Bo[ntp][s], acc[1][ntp], 0, 0, 0);
        }
    }
#pragma unroll
    for (int mt = 0; mt < 2; ++mt)
#pragma unroll
        for (int ntp = 0; ntp < 2; ++ntp)
#pragma unroll
            for (int r = 0; r < 4; ++r) {
                int row = 16 * mt + 4 * g + r;
                if (n0 + row < NB)
                    out[(size_t)(n0 + row) * NH + li + 32 * w + 16 * ntp] = acc[mt][ntp][r] + bo[ntp];
            }
}

// ---------------- K2 main: wave-per-node, barrier-free, weights in LDS blobs ----------------
__global__ void __launch_bounds__(256, 2) vibgat_main2(
    const float* __restrict__ neighbor_feat, const float* __restrict__ trust_mask,
    const float* __restrict__ eps,
    const float* __restrict__ pre_g, const float* __restrict__ pre_b,
    const float* __restrict__ W_mu, const float* __restrict__ b_mu,
    const float* __restrict__ W_lv, const float* __restrict__ b_lv,
    const float* __restrict__ post_g, const float* __restrict__ post_b,
    const float* __restrict__ W_k, const float* __restrict__ W_v,
    const float* __restrict__ b_v,
    const unsigned short* __restrict__ q_ws, float* __restrict__ ctx_ws,
    float* __restrict__ out)
{
    __shared__ uint4 WmlB[8 * 4 * 64];                         // 32KB  [nt][s][lane]
    __shared__ uint4 WkvB[8 * 2 * 64];                         // 16KB  [nt][s][lane]
    __shared__ __align__(16) unsigned short z_all[4][32 * 64]; // 16KB per-wave z, swizzled
    __shared__ float2 s_pgb[128];                              // 1KB (pre_g, pre_b)
    __shared__ float klw[4];

    const int t = threadIdx.x;
    const int w = t >> 6, l = t & 63, g = l >> 4, li = l & 15;

    if (t < 128) s_pgb[t] = make_float2(pre_g[t], pre_b[t]);
    for (int e = t; e < 2048; e += 256) {   // WmlB: nt 0..3 = W_mu, 4..7 = W_lv
        int nt = e >> 8, s = (e >> 6) & 3, ln = e & 63;
        const float* src = (nt < 4) ? W_mu : W_lv;
        int gg = ln >> 4, ll = ln & 15, c = ll + 16 * (nt & 3);
        unsigned int p[4];
#pragma unroll
        for (int jp = 0; jp < 4; ++jp) {
            int k = 32 * s + 8 * gg + 2 * jp;
            p[jp] = (unsigned)f2bf(src[k * 64 + c]) | ((unsigned)f2bf(src[(k + 1) * 64 + c]) << 16);
        }
        WmlB[e] = make_uint4(p[0], p[1], p[2], p[3]);
    }
    for (int e = t; e < 1024; e += 256) {   // WkvB: nt 0..3 = W_k, 4..7 = W_v
        int nt = e >> 7, s = (e >> 6) & 1, ln = e & 63;
        const float* src = (nt < 4) ? W_k : W_v;
        int gg = ln >> 4, ll = ln & 15, c = ll + 16 * (nt & 3);
        unsigned int p[4];
#pragma unroll
        for (int jp = 0; jp < 4; ++jp) {
            int k = 32 * s + 8 * gg + 2 * jp;
            p[jp] = (unsigned)f2bf(src[k * 64 + c]) | ((unsigned)f2bf(src[(k + 1) * 64 + c]) << 16);
        }
        WkvB[e] = make_uint4(p[0], p[1], p[2], p[3]);
    }
    float bmu4[4], blv4[4], pg4[4], pb4[4], bv4[4];
#pragma unroll
    for (int nt = 0; nt < 4; ++nt) {
        int c = li + 16 * nt;
        bmu4[nt] = b_mu[c]; blv4[nt] = b_lv[c];
        pg4[nt] = post_g[c]; pb4[nt] = post_b[c]; bv4[nt] = b_v[c];
    }
    __syncthreads();

    unsigned short* zl = &z_all[w][0];
    const f32x4 zero4 = {0.f, 0.f, 0.f, 0.f};
    const int stride = gridDim.x * 4;
    int bn = blockIdx.x * 4 + w;

    f32x4 nbr[2][4][2];      // prefetched neighbor rows li,16+li cols 32s+8g+4h..
    float epr[2][4][4];      // eps in MFMA-C layout
    float q4[4];             // q for this node (from q_ws)
    float trr;               // raw trust[l&31]

    {   // prologue prefetch
        const float* base = neighbor_feat + ((size_t)bn * NK + li) * NH + 8 * g;
#pragma unroll
        for (int t2 = 0; t2 < 2; ++t2)
#pragma unroll
            for (int s = 0; s < 4; ++s)
#pragma unroll
                for (int h = 0; h < 2; ++h)
                    nbr[t2][s][h] = *(const f32x4*)(base + (size_t)t2 * 16 * NH + 32 * s + 4 * h);
        const float* eb = eps + ((size_t)bn * NK + 4 * g) * NL + li;
#pragma unroll
        for (int mt = 0; mt < 2; ++mt)
#pragma unroll
            for (int nt = 0; nt < 4; ++nt)
#pragma unroll
                for (int r = 0; r < 4; ++r)
                    epr[mt][nt][r] = eb[(size_t)(16 * mt + r) * NL + 16 * nt];
#pragma unroll
        for (int nt = 0; nt < 4; ++nt) q4[nt] = bf2f(q_ws[(size_t)bn * 64 + li + 16 * nt]);
        trr = trust_mask[(size_t)bn * NK + (l & 31)];
    }

    float kl_acc = 0.f;

    for (; bn < NB; bn += stride) {
        const int nxt = (bn + stride < NB) ? (bn + stride) : bn;

        // ---------- LN -> A-fragments in registers ----------
        float s0 = 0.f, s1 = 0.f;
#pragma unroll
        for (int s = 0; s < 4; ++s)
#pragma unroll
            for (int h = 0; h < 2; ++h) {
                f32x4 v0 = nbr[0][s][h], v1 = nbr[1][s][h];
                s0 += v0[0] + v0[1] + v0[2] + v0[3];
                s1 += v1[0] + v1[1] + v1[2] + v1[3];
            }
        s0 += __shfl_xor(s0, 16); s0 += __shfl_xor(s0, 32);
        s1 += __shfl_xor(s1, 16); s1 += __shfl_xor(s1, 32);
        float m0 = s0 * (1.f / 128.f), m1 = s1 * (1.f / 128.f);
        float v0s = 0.f, v1s = 0.f;
#pragma unroll
        for (int s = 0; s < 4; ++s)
#pragma unroll
            for (int h = 0; h < 2; ++h)
#pragma unroll
                for (int c = 0; c < 4; ++c) {
                    float d0 = nbr[0][s][h][c] - m0; v0s += d0 * d0;
                    float d1 = nbr[1][s][h][c] - m1; v1s += d1 * d1;
                }
        v0s += __shfl_xor(v0s, 16); v0s += __shfl_xor(v0s, 32);
        v1s += __shfl_xor(v1s, 16); v1s += __shfl_xor(v1s, 32);
        float inv0 = rsqrtf(v0s * (1.f / 128.f) + 1e-5f);
        float inv1 = rsqrtf(v1s * (1.f / 128.f) + 1e-5f);
        bf16x8 a0[4], a1[4];
#pragma unroll
        for (int s = 0; s < 4; ++s) {
            const float2* gbp = &s_pgb[32 * s + 8 * g];
#pragma unroll
            for (int h = 0; h < 2; ++h)
#pragma unroll
                for (int c = 0; c < 4; ++c) {
                    int j = 4 * h + c;
                    float2 gb = gbp[j];
                    a0[s][j] = (short)f2bf((nbr[0][s][h][c] - m0) * inv0 * gb.x + gb.y);
                    a1[s][j] = (short)f2bf((nbr[1][s][h][c] - m1) * inv1 * gb.x + gb.y);
                }
        }
        {   // reissue neighbor loads for next node
            const float* base = neighbor_feat + ((size_t)nxt * NK + li) * NH + 8 * g;
#pragma unroll
            for (int t2 = 0; t2 < 2; ++t2)
#pragma unroll
                for (int s = 0; s < 4; ++s)
#pragma unroll
                    for (int h = 0; h < 2; ++h)
                        nbr[t2][s][h] = *(const f32x4*)(base + (size_t)t2 * 16 * NH + 32 * s + 4 * h);
        }

        // ---------- GEMM1: mu|lv (B-frags from LDS blob) ----------
        f32x4 acc1[2][8];
#pragma unroll
        for (int mt = 0; mt < 2; ++mt)
#pragma unroll
            for (int nt = 0; nt < 8; ++nt) acc1[mt][nt] = zero4;
#pragma unroll
        for (int s = 0; s < 4; ++s)
#pragma unroll
            for (int nt = 0; nt < 8; ++nt) {
                bf16x8 fb = *(const bf16x8*)&WmlB[(nt * 4 + s) * 64 + l];
                acc1[0][nt] = __builtin_amdgcn_mfma_f32_16x16x32_bf16(a0[s], fb, acc1[0][nt], 0, 0, 0);
                acc1[1][nt] = __builtin_amdgcn_mfma_f32_16x16x32_bf16(a1[s], fb, acc1[1][nt], 0, 0, 0);
            }

        // ---------- reparam + KL + post-LN -> z LDS ----------
#pragma unroll
        for (int mt = 0; mt < 2; ++mt)
#pragma unroll
            for (int nt = 0; nt < 4; ++nt)
#pragma unroll
                for (int r = 0; r < 4; ++r) {
                    float mu = acc1[mt][nt][r] + bmu4[nt];
                    float lv = acc1[mt][nt + 4][r] + blv4[nt];
                    float eh = __expf(0.5f * lv);
                    kl_acc += 1.f + lv - mu * mu - eh * eh;
                    acc1[mt][nt][r] = mu + epr[mt][nt][r] * eh;
                }
#pragma unroll
        for (int mt = 0; mt < 2; ++mt)
#pragma unroll
            for (int r = 0; r < 4; ++r) {
                float s1 = acc1[mt][0][r] + acc1[mt][1][r] + acc1[mt][2][r] + acc1[mt][3][r];
                s1 += __shfl_xor(s1, 1); s1 += __shfl_xor(s1, 2);
                s1 += __shfl_xor(s1, 4); s1 += __shfl_xor(s1, 8);
                float mean = s1 * (1.f / 64.f);
                float s2 = 0.f;
#pragma unroll
                for (int nt = 0; nt < 4; ++nt) { float d = acc1[mt][nt][r] - mean; s2 += d * d; }
                s2 += __shfl_xor(s2, 1); s2 += __shfl_xor(s2, 2);
                s2 += __shfl_xor(s2, 4); s2 += __shfl_xor(s2, 8);
                float inv = rsqrtf(s2 * (1.f / 64.f) + 1e-5f);
                int row = 16 * mt + 4 * g + r;
#pragma unroll
                for (int nt = 0; nt < 4; ++nt) {
                    unsigned short zb = f2bf((acc1[mt][nt][r] - mean) * inv * pg4[nt] + pb4[nt]);
                    *(unsigned short*)((char*)zl + ((row * 128 + (li + 16 * nt) * 2) ^ ((row & 7) << 4))) = zb;
                }
            }
        {   // reissue eps for next node
            const float* eb = eps + ((size_t)nxt * NK + 4 * g) * NL + li;
#pragma unroll
            for (int mt = 0; mt < 2; ++mt)
#pragma unroll
                for (int nt = 0; nt < 4; ++nt)
#pragma unroll
                    for (int r = 0; r < 4; ++r)
                        epr[mt][nt][r] = eb[(size_t)(16 * mt + r) * NL + 16 * nt];
        }

        // ---------- GEMM2: k|v + attention ----------
        f32x4 acc2[2][8];
#pragma unroll
        for (int mt = 0; mt < 2; ++mt)
#pragma unroll
            for (int nt = 0; nt < 8; ++nt) acc2[mt][nt] = zero4;
#pragma unroll
        for (int s = 0; s < 2; ++s) {
            bf16x8 A0 = *(const bf16x8*)((const char*)zl + ((li * 128 + s * 64 + g * 16) ^ ((li & 7) << 4)));
            bf16x8 A1 = *(const bf16x8*)((const char*)zl + (((16 + li) * 128 + s * 64 + g * 16) ^ (((16 + li) & 7) << 4)));
#pragma unroll
            for (int nt = 0; nt < 8; ++nt) {
                bf16x8 fb = *(const bf16x8*)&WkvB[(nt * 2 + s) * 64 + l];
                acc2[0][nt] = __builtin_amdgcn_mfma_f32_16x16x32_bf16(A0, fb, acc2[0][nt], 0, 0, 0);
                acc2[1][nt] = __builtin_amdgcn_mfma_f32_16x16x32_bf16(A1, fb, acc2[1][nt], 0, 0, 0);
            }
        }
        float trlog = __logf(trr + 1e-6f);
        float att[2][4];
#pragma unroll
        for (int mt = 0; mt < 2; ++mt)
#pragma unroll
            for (int r = 0; r < 4; ++r) {
                float p = q4[0] * acc2[mt][0][r] + q4[1] * acc2[mt][1][r]
                        + q4[2] * acc2[mt][2][r] + q4[3] * acc2[mt][3][r];
                p += __shfl_xor(p, 1); p += __shfl_xor(p, 2);
                p += __shfl_xor(p, 4); p += __shfl_xor(p, 8);
                att[mt][r] = p * 0.125f + __shfl(trlog, 16 * mt + 4 * g + r);
            }
        // reissue q and trust for next node (q4 consumed above)
#pragma unroll
        for (int nt = 0; nt < 4; ++nt) q4[nt] = bf2f(q_ws[(size_t)nxt * 64 + li + 16 * nt]);
        trr = trust_mask[(size_t)nxt * NK + (l & 31)];

        float m = att[0][0];
#pragma unroll
        for (int mt = 0; mt < 2; ++mt)
#pragma unroll
            for (int r = 0; r < 4; ++r) m = fmaxf(m, att[mt][r]);
        m = fmaxf(m, __shfl_xor(m, 16)); m = fmaxf(m, __shfl_xor(m, 32));
        float den = 0.f;
#pragma unroll
        for (int mt = 0; mt < 2; ++mt)
#pragma unroll
            for (int r = 0; r < 4; ++r) { att[mt][r] = __expf(att[mt][r] - m); den += att[mt][r]; }
        den += __shfl_xor(den, 16); den += __shfl_xor(den, 32);
        float idn = 1.f / den;
#pragma unroll
        for (int nt = 0; nt < 4; ++nt) {
            float cx = 0.f;
#pragma unroll
            for (int mt = 0; mt < 2; ++mt)
#pragma unroll
                for (int r = 0; r < 4; ++r) cx += att[mt][r] * idn * acc2[mt][nt + 4][r];
            cx += __shfl_xor(cx, 16); cx += __shfl_xor(cx, 32);
            if (g == 0) ctx_ws[(size_t)bn * 64 + li + 16 * nt] = cx + bv4[nt];
        }
    }

    // ---------- KL reduction ----------
#pragma unroll
    for (int msk = 1; msk < 64; msk <<= 1) kl_acc += __shfl_xor(kl_acc, msk);
    if (l == 0) klw[w] = kl_acc;
    __syncthreads();
    if (t == 0) {
        float tot = klw[0] + klw[1] + klw[2] + klw[3];
        atomicAdd(out + (size_t)NB * NH, tot * (-0.5f * 0.001f / ((float)NB * NK)));
    }
}

extern "C" void kernel_launch(void* const* d_in, const int* in_sizes, int n_in,
                              void* d_out, int out_size, void* d_ws, size_t ws_size,
                              hipStream_t stream) {
    const float* self_feat     = (const float*)d_in[0];
    const float* neighbor_feat = (const float*)d_in[1];
    const float* trust_mask    = (const float*)d_in[2];
    const float* eps           = (const float*)d_in[3];
    const float* pre_g  = (const float*)d_in[4];
    const float* pre_b  = (const float*)d_in[5];
    const float* W_mu   = (const float*)d_in[6];
    const float* b_mu   = (const float*)d_in[7];
    const float* W_lv   = (const float*)d_in[8];
    const float* b_lv   = (const float*)d_in[9];
    const float* post_g = (const float*)d_in[10];
    const float* post_b = (const float*)d_in[11];
    const float* W_q    = (const float*)d_in[12];
    const float* b_q    = (const float*)d_in[13];
    const float* W_k    = (const float*)d_in[14];
    const float* W_v    = (const float*)d_in[16];
    const float* b_v    = (const float*)d_in[17];
    const float* W_o    = (const float*)d_in[18];
    const float* b_o    = (const float*)d_in[19];
    float* out = (float*)d_out;

    // workspace: q (bf16, 6.4MB) then ctx (f32, 12.8MB)
    unsigned short* q_ws = (unsigned short*)d_ws;
    float* ctx_ws = (float*)((char*)d_ws + (size_t)NB * NL * sizeof(unsigned short));

    const int ntiles = (NB + 31) / 32;   // 1563
    hipLaunchKernelGGL(kl_zero_kernel, dim3(1), dim3(64), 0, stream, out);
    hipLaunchKernelGGL(q_kernel, dim3(ntiles), dim3(256), 0, stream, self_feat, W_q, b_q, q_ws);
    hipLaunchKernelGGL(vibgat_main2, dim3(512), dim3(256), 0, stream,
                       neighbor_feat, trust_mask, eps, pre_g, pre_b,
                       W_mu, b_mu, W_lv, b_lv, post_g, post_b,
                       W_k, W_v, b_v, q_ws, ctx_ws, out);
    hipLaunchKernelGGL(out_kernel, dim3(ntiles), dim3(256), 0, stream, ctx_ws, W_o, b_o, out);
}

// Round 6
// 433.046 us; speedup vs baseline: 5.3763x; 2.4989x over previous
//
#include <hip/hip_runtime.h>
#include <hip/hip_bf16.h>

typedef float f32x4 __attribute__((ext_vector_type(4)));
typedef short bf16x8 __attribute__((ext_vector_type(8)));

#define NB 50000
#define NK 32
#define NH 128
#define NL 64

static __device__ __forceinline__ unsigned short f2bf(float f) {
    unsigned int u = __float_as_uint(f);
    u += 0x7fffu + ((u >> 16) & 1u);
    return (unsigned short)(u >> 16);
}
static __device__ __forceinline__ float bf2f(unsigned short u) {
    return __uint_as_float(((unsigned int)u) << 16);
}
static __device__ __forceinline__ float bflo(unsigned int u) { return __uint_as_float(u << 16); }
static __device__ __forceinline__ float bfhi(unsigned int u) { return __uint_as_float(u & 0xffff0000u); }

__global__ void kl_zero_kernel(float* out) {
    if (threadIdx.x == 0 && blockIdx.x == 0) out[(size_t)NB * NH] = 0.0f;
}

// ---------------- K1: q_all = self_feat @ W_q + b_q  (bf16 out to ws) ----------------
__global__ void __launch_bounds__(256) q_kernel(const float* __restrict__ self_feat,
                                                const float* __restrict__ W_q,
                                                const float* __restrict__ b_q,
                                                unsigned short* __restrict__ q_ws)
{
    __shared__ __align__(16) unsigned short A[32 * 128];   // bf16 swizzled, row stride 256B
    const int t = threadIdx.x, w = t >> 6, l = t & 63, g = l >> 4, li = l & 15;

    bf16x8 Bq[4];
#pragma unroll
    for (int s = 0; s < 4; ++s) {
        int k0 = 32 * s + 8 * g, c = li + 16 * w;
        bf16x8 f;
#pragma unroll
        for (int j = 0; j < 8; ++j) f[j] = (short)f2bf(W_q[(k0 + j) * 64 + c]);
        Bq[s] = f;
    }
    const float bq = b_q[li + 16 * w];
    const int n0 = blockIdx.x * 32;

    {
        int row = t >> 3, c0 = (t & 7) * 16;
        float x[16];
        if (n0 + row < NB) {
            const float* src = self_feat + (size_t)(n0 + row) * NH + c0;
#pragma unroll
            for (int i = 0; i < 4; ++i) {
                float4 v4 = ((const float4*)src)[i];
                x[4 * i] = v4.x; x[4 * i + 1] = v4.y; x[4 * i + 2] = v4.z; x[4 * i + 3] = v4.w;
            }
        } else {
#pragma unroll
            for (int i = 0; i < 16; ++i) x[i] = 0.f;
        }
        alignas(16) unsigned short yb[16];
#pragma unroll
        for (int i = 0; i < 16; ++i) yb[i] = f2bf(x[i]);
        int boff = row * 256 + c0 * 2;
        *(int4*)((char*)A + ((boff) ^ ((row & 7) << 4))) = *(int4*)&yb[0];
        *(int4*)((char*)A + ((boff + 16) ^ ((row & 7) << 4))) = *(int4*)&yb[8];
    }
    __syncthreads();

    const f32x4 zero4 = {0.f, 0.f, 0.f, 0.f};
    f32x4 acc[2] = {zero4, zero4};
#pragma unroll
    for (int s = 0; s < 4; ++s) {
        bf16x8 A0 = *(const bf16x8*)((const char*)A + ((li * 256 + s * 64 + g * 16) ^ ((li & 7) << 4)));
        bf16x8 A1 = *(const bf16x8*)((const char*)A + (((16 + li) * 256 + s * 64 + g * 16) ^ ((li & 7) << 4)));
        acc[0] = __builtin_amdgcn_mfma_f32_16x16x32_bf16(A0, Bq[s], acc[0], 0, 0, 0);
        acc[1] = __builtin_amdgcn_mfma_f32_16x16x32_bf16(A1, Bq[s], acc[1], 0, 0, 0);
    }
#pragma unroll
    for (int mt = 0; mt < 2; ++mt)
#pragma unroll
        for (int r = 0; r < 4; ++r) {
            int row = 16 * mt + 4 * g + r;
            if (n0 + row < NB)
                q_ws[(size_t)(n0 + row) * 64 + li + 16 * w] = f2bf(acc[mt][r] + bq);
        }
}

// ---------------- K_A: LN -> GEMM1(mu|lv) -> reparam+KL -> post-LN -> z (bf16, ws) ----------
// Block = 256 threads, 8 nodes per block, cooperative phases, 2 barriers/node.
__global__ void __launch_bounds__(256) ka_kernel(
    const float* __restrict__ neighbor_feat, const float* __restrict__ eps_g,
    const float* __restrict__ pre_g, const float* __restrict__ pre_b,
    const float* __restrict__ W_mu, const float* __restrict__ b_mu,
    const float* __restrict__ W_lv, const float* __restrict__ b_lv,
    const float* __restrict__ post_g, const float* __restrict__ post_b,
    unsigned short* __restrict__ z_ws, float* __restrict__ out,
    int nbeg, int ncnt)
{
    __shared__ __align__(16) unsigned short A[32 * 128];  // 8KB bf16 swizzled
    __shared__ float muv[32 * 136];                       // 17.4KB (stride 136: ~2-way banks)
    __shared__ float2 s_pgb[128];
    __shared__ float s_bmu[64], s_blv[64], s_pg[64], s_pb[64];
    __shared__ float klw[4];

    const int t = threadIdx.x, w = t >> 6, l = t & 63, g = l >> 4, li = l & 15;

    if (t < 128) s_pgb[t] = make_float2(pre_g[t], pre_b[t]);
    if (t < 64) { s_bmu[t] = b_mu[t]; s_blv[t] = b_lv[t]; s_pg[t] = post_g[t]; s_pb[t] = post_b[t]; }

    // per-wave weight B-frags: wave 0,1 -> W_mu cols 0-31/32-63; wave 2,3 -> W_lv cols 0-31/32-63
    bf16x8 Wml[2][4];
    {
        const float* Wsrc = (w < 2) ? W_mu : W_lv;
        int cb = 32 * (w & 1) + li;
#pragma unroll
        for (int ntp = 0; ntp < 2; ++ntp)
#pragma unroll
            for (int s = 0; s < 4; ++s) {
                int k0 = 32 * s + 8 * g, c = cb + 16 * ntp;
                bf16x8 f;
#pragma unroll
                for (int j = 0; j < 8; ++j) f[j] = (short)f2bf(Wsrc[(k0 + j) * 64 + c]);
                Wml[ntp][s] = f;
            }
    }
    __syncthreads();

    const int row = t >> 3;          // 0..31
    const int c0 = (t & 7) * 16;     // P0 col group
    const int l0 = (t & 7) * 8;      // P2 col group
    const int nend = nbeg + ncnt;
    int bn = nbeg + blockIdx.x * 8;

    float x[16], ee[8];
    {   // prologue prefetch (clamped)
        int bs = (bn < nend) ? bn : nbeg;
        const float* src = neighbor_feat + ((size_t)bs * NK + row) * NH + c0;
#pragma unroll
        for (int i = 0; i < 4; ++i) {
            float4 v4 = ((const float4*)src)[i];
            x[4 * i] = v4.x; x[4 * i + 1] = v4.y; x[4 * i + 2] = v4.z; x[4 * i + 3] = v4.w;
        }
        const float* ep = eps_g + ((size_t)bs * NK + row) * NL + l0;
        float4 e0 = ((const float4*)ep)[0], e1 = ((const float4*)ep)[1];
        ee[0] = e0.x; ee[1] = e0.y; ee[2] = e0.z; ee[3] = e0.w;
        ee[4] = e1.x; ee[5] = e1.y; ee[6] = e1.z; ee[7] = e1.w;
    }

    float kl_acc = 0.f;
    const f32x4 zero4 = {0.f, 0.f, 0.f, 0.f};

    for (int i = 0; i < 8; ++i, ++bn) {
        const bool live = (bn < nend);
        const int bnx = (bn + 1 < nend) ? bn + 1 : nbeg;   // next prefetch target (clamped)

        // ---- P0: pre-LN on x -> bf16 A tile ----
        float s1 = 0.f;
#pragma unroll
        for (int j = 0; j < 16; ++j) s1 += x[j];
        s1 += __shfl_xor(s1, 1); s1 += __shfl_xor(s1, 2); s1 += __shfl_xor(s1, 4);
        float mean = s1 * (1.f / 128.f);
        float s2 = 0.f;
#pragma unroll
        for (int j = 0; j < 16; ++j) { float d = x[j] - mean; s2 += d * d; }
        s2 += __shfl_xor(s2, 1); s2 += __shfl_xor(s2, 2); s2 += __shfl_xor(s2, 4);
        float inv = rsqrtf(s2 * (1.f / 128.f) + 1e-5f);
        alignas(16) unsigned short yb[16];
#pragma unroll
        for (int j = 0; j < 16; ++j) {
            float2 gb = s_pgb[c0 + j];
            yb[j] = f2bf((x[j] - mean) * inv * gb.x + gb.y);
        }
        {
            int boff = row * 256 + c0 * 2;
            *(int4*)((char*)A + ((boff) ^ ((row & 7) << 4))) = *(int4*)&yb[0];
            *(int4*)((char*)A + ((boff + 16) ^ ((row & 7) << 4))) = *(int4*)&yb[8];
        }
        {   // reissue x for next node (x consumed)
            const float* src = neighbor_feat + ((size_t)bnx * NK + row) * NH + c0;
#pragma unroll
            for (int j = 0; j < 4; ++j) {
                float4 v4 = ((const float4*)src)[j];
                x[4 * j] = v4.x; x[4 * j + 1] = v4.y; x[4 * j + 2] = v4.z; x[4 * j + 3] = v4.w;
            }
        }
        __syncthreads();

        // ---- P1: GEMM1, wave w covers cols 32w..32w+31 of [mu|lv] ----
        f32x4 acc[2][2];
        acc[0][0] = zero4; acc[0][1] = zero4; acc[1][0] = zero4; acc[1][1] = zero4;
#pragma unroll
        for (int s = 0; s < 4; ++s) {
            bf16x8 A0 = *(const bf16x8*)((const char*)A + ((li * 256 + s * 64 + g * 16) ^ ((li & 7) << 4)));
            bf16x8 A1 = *(const bf16x8*)((const char*)A + (((16 + li) * 256 + s * 64 + g * 16) ^ ((li & 7) << 4)));
#pragma unroll
            for (int ntp = 0; ntp < 2; ++ntp) {
                acc[0][ntp] = __builtin_amdgcn_mfma_f32_16x16x32_bf16(A0, Wml[ntp][s], acc[0][ntp], 0, 0, 0);
                acc[1][ntp] = __builtin_amdgcn_mfma_f32_16x16x32_bf16(A1, Wml[ntp][s], acc[1][ntp], 0, 0, 0);
            }
        }
#pragma unroll
        for (int mt = 0; mt < 2; ++mt)
#pragma unroll
            for (int ntp = 0; ntp < 2; ++ntp)
#pragma unroll
                for (int r = 0; r < 4; ++r)
                    muv[(16 * mt + 4 * g + r) * 136 + 32 * w + 16 * ntp + li] = acc[mt][ntp][r];
        __syncthreads();

        // ---- P2: reparam + KL + post-LN -> z bf16 to global ws ----
        f32x4 mu0 = *(const f32x4*)&muv[row * 136 + l0];
        f32x4 mu1 = *(const f32x4*)&muv[row * 136 + l0 + 4];
        f32x4 lv0 = *(const f32x4*)&muv[row * 136 + 64 + l0];
        f32x4 lv1 = *(const f32x4*)&muv[row * 136 + 64 + l0 + 4];
        float zr[8];
#pragma unroll
        for (int j = 0; j < 8; ++j) {
            float mu = ((j < 4) ? mu0[j & 3] : mu1[j & 3]) + s_bmu[l0 + j];
            float lv = ((j < 4) ? lv0[j & 3] : lv1[j & 3]) + s_blv[l0 + j];
            float eh = __expf(0.5f * lv);
            if (live) kl_acc += 1.f + lv - mu * mu - eh * eh;
            zr[j] = mu + ee[j] * eh;
        }
        {   // reissue eps for next node (ee consumed)
            const float* ep = eps_g + ((size_t)bnx * NK + row) * NL + l0;
            float4 e0 = ((const float4*)ep)[0], e1 = ((const float4*)ep)[1];
            ee[0] = e0.x; ee[1] = e0.y; ee[2] = e0.z; ee[3] = e0.w;
            ee[4] = e1.x; ee[5] = e1.y; ee[6] = e1.z; ee[7] = e1.w;
        }
        float zs = 0.f;
#pragma unroll
        for (int j = 0; j < 8; ++j) zs += zr[j];
        zs += __shfl_xor(zs, 1); zs += __shfl_xor(zs, 2); zs += __shfl_xor(zs, 4);
        float zm = zs * (1.f / 64.f);
        float zv = 0.f;
#pragma unroll
        for (int j = 0; j < 8; ++j) { float d = zr[j] - zm; zv += d * d; }
        zv += __shfl_xor(zv, 1); zv += __shfl_xor(zv, 2); zv += __shfl_xor(zv, 4);
        float zi = rsqrtf(zv * (1.f / 64.f) + 1e-5f);
        alignas(16) unsigned short zb[8];
#pragma unroll
        for (int j = 0; j < 8; ++j)
            zb[j] = f2bf((zr[j] - zm) * zi * s_pg[l0 + j] + s_pb[l0 + j]);
        if (live)
            *(int4*)(z_ws + (size_t)(bn - nbeg) * (NK * NL) + row * NL + l0) = *(int4*)zb;
        // no barrier needed: next P0 writes A (readers done pre-P2-barrier); muv rewritten only after next barrier
    }

    // ---- KL reduction ----
#pragma unroll
    for (int msk = 1; msk < 64; msk <<= 1) kl_acc += __shfl_xor(kl_acc, msk);
    if (l == 0) klw[w] = kl_acc;
    __syncthreads();
    if (t == 0) {
        float tot = klw[0] + klw[1] + klw[2] + klw[3];
        atomicAdd(out + (size_t)NB * NH, tot * (-0.5f * 0.001f / ((float)NB * NK)));
    }
}

// ---------------- K_B: z -> k|v GEMM -> attention -> ctx -> out-proj (fused) -------------
// Persistent, wave-per-node, no in-loop barriers. z-frags loaded directly from global.
__global__ void __launch_bounds__(256) kb_kernel(
    const unsigned short* __restrict__ z_ws, const float* __restrict__ trust_mask,
    const unsigned short* __restrict__ q_ws,
    const float* __restrict__ W_k, const float* __restrict__ W_v,
    const float* __restrict__ b_v,
    const float* __restrict__ W_o, const float* __restrict__ b_o,
    float* __restrict__ out, int nbeg, int ncnt)
{
    __shared__ uint4 WkvB[8 * 2 * 64];   // 16KB  [nt][s][lane] frag blob (nt<4=W_k, else W_v)
    __shared__ uint2 WoP[32 * 64];       // 16KB  W_o packed [c2][h'] (lo=h, hi=h+64)
    __shared__ float ctxl[4][64];

    const int t = threadIdx.x, w = t >> 6, l = t & 63, g = l >> 4, li = l & 15;

    for (int e = t; e < 1024; e += 256) {
        int nt = e >> 7, s = (e >> 6) & 1, ln = e & 63;
        const float* src = (nt < 4) ? W_k : W_v;
        int gg = ln >> 4, ll = ln & 15, c = ll + 16 * (nt & 3);
        unsigned int p[4];
#pragma unroll
        for (int jp = 0; jp < 4; ++jp) {
            int k = 32 * s + 8 * gg + 2 * jp;
            p[jp] = (unsigned)f2bf(src[k * 64 + c]) | ((unsigned)f2bf(src[(k + 1) * 64 + c]) << 16);
        }
        WkvB[e] = make_uint4(p[0], p[1], p[2], p[3]);
    }
    for (int e = t; e < 2048; e += 256) {
        int c2 = e >> 6, h = e & 63;
        unsigned int w0 = (unsigned)f2bf(W_o[(2 * c2) * 128 + h]) | ((unsigned)f2bf(W_o[(2 * c2) * 128 + h + 64]) << 16);
        unsigned int w1 = (unsigned)f2bf(W_o[(2 * c2 + 1) * 128 + h]) | ((unsigned)f2bf(W_o[(2 * c2 + 1) * 128 + h + 64]) << 16);
        WoP[e] = make_uint2(w0, w1);
    }
    float bv4[4];
#pragma unroll
    for (int nt = 0; nt < 4; ++nt) bv4[nt] = b_v[li + 16 * nt];
    const float bo0 = b_o[l], bo1 = b_o[64 + l];
    __syncthreads();

    const int nend = nbeg + ncnt;
    const int stride = gridDim.x * 4;
    int bn = nbeg + blockIdx.x * 4 + w;

    bf16x8 za0[2], za1[2];
    float q4[4], trr;
    {   // prologue prefetch (clamped)
        int bs = (bn < nend) ? bn : nbeg;
        const unsigned short* zp = z_ws + (size_t)(bs - nbeg) * (NK * NL);
#pragma unroll
        for (int s = 0; s < 2; ++s) {
            za0[s] = *(const bf16x8*)(zp + li * NL + 32 * s + 8 * g);
            za1[s] = *(const bf16x8*)(zp + (16 + li) * NL + 32 * s + 8 * g);
        }
#pragma unroll
        for (int nt = 0; nt < 4; ++nt) q4[nt] = bf2f(q_ws[(size_t)bs * 64 + li + 16 * nt]);
        trr = trust_mask[(size_t)bs * NK + (l & 31)];
    }

    const f32x4 zero4 = {0.f, 0.f, 0.f, 0.f};

    for (; bn < nend; bn += stride) {
        const int nx = (bn + stride < nend) ? bn + stride : bn;

        // ---- k GEMM (acc 32 regs) ----
        f32x4 acck[2][4];
#pragma unroll
        for (int mt = 0; mt < 2; ++mt)
#pragma unroll
            for (int nt = 0; nt < 4; ++nt) acck[mt][nt] = zero4;
#pragma unroll
        for (int s = 0; s < 2; ++s)
#pragma unroll
            for (int nt = 0; nt < 4; ++nt) {
                bf16x8 fb = *(const bf16x8*)&WkvB[(nt * 2 + s) * 64 + l];
                acck[0][nt] = __builtin_amdgcn_mfma_f32_16x16x32_bf16(za0[s], fb, acck[0][nt], 0, 0, 0);
                acck[1][nt] = __builtin_amdgcn_mfma_f32_16x16x32_bf16(za1[s], fb, acck[1][nt], 0, 0, 0);
            }
        float trlog = __logf(trr + 1e-6f);
        float att[2][4];
#pragma unroll
        for (int mt = 0; mt < 2; ++mt)
#pragma unroll
            for (int r = 0; r < 4; ++r) {
                float p = q4[0] * acck[mt][0][r] + q4[1] * acck[mt][1][r]
                        + q4[2] * acck[mt][2][r] + q4[3] * acck[mt][3][r];
                p += __shfl_xor(p, 1); p += __shfl_xor(p, 2);
                p += __shfl_xor(p, 4); p += __shfl_xor(p, 8);
                att[mt][r] = p * 0.125f + __shfl(trlog, 16 * mt + 4 * g + r);
            }
        float m = att[0][0];
#pragma unroll
        for (int mt = 0; mt < 2; ++mt)
#pragma unroll
            for (int r = 0; r < 4; ++r) m = fmaxf(m, att[mt][r]);
        m = fmaxf(m, __shfl_xor(m, 16)); m = fmaxf(m, __shfl_xor(m, 32));
        float den = 0.f;
#pragma unroll
        for (int mt = 0; mt < 2; ++mt)
#pragma unroll
            for (int r = 0; r < 4; ++r) { att[mt][r] = __expf(att[mt][r] - m); den += att[mt][r]; }
        den += __shfl_xor(den, 16); den += __shfl_xor(den, 32);
        float idn = 1.f / den;

        // ---- v GEMM (acck dead except via att; acc reuse keeps peak ~64) ----
        f32x4 accv[2][4];
#pragma unroll
        for (int mt = 0; mt < 2; ++mt)
#pragma unroll
            for (int nt = 0; nt < 4; ++nt) accv[mt][nt] = zero4;
#pragma unroll
        for (int s = 0; s < 2; ++s)
#pragma unroll
            for (int nt = 0; nt < 4; ++nt) {
                bf16x8 fb = *(const bf16x8*)&WkvB[((nt + 4) * 2 + s) * 64 + l];
                accv[0][nt] = __builtin_amdgcn_mfma_f32_16x16x32_bf16(za0[s], fb, accv[0][nt], 0, 0, 0);
                accv[1][nt] = __builtin_amdgcn_mfma_f32_16x16x32_bf16(za1[s], fb, accv[1][nt], 0, 0, 0);
            }
        {   // prefetch next node (za/q/tr consumed)
            const unsigned short* zp = z_ws + (size_t)(nx - nbeg) * (NK * NL);
#pragma unroll
            for (int s = 0; s < 2; ++s) {
                za0[s] = *(const bf16x8*)(zp + li * NL + 32 * s + 8 * g);
                za1[s] = *(const bf16x8*)(zp + (16 + li) * NL + 32 * s + 8 * g);
            }
#pragma unroll
            for (int nt = 0; nt < 4; ++nt) q4[nt] = bf2f(q_ws[(size_t)nx * 64 + li + 16 * nt]);
            trr = trust_mask[(size_t)nx * NK + (l & 31)];
        }

        // ---- ctx (b_v folded: sum(attn)=1) ----
#pragma unroll
        for (int nt = 0; nt < 4; ++nt) {
            float cx = 0.f;
#pragma unroll
            for (int mt = 0; mt < 2; ++mt)
#pragma unroll
                for (int r = 0; r < 4; ++r) cx += att[mt][r] * idn * accv[mt][nt][r];
            cx += __shfl_xor(cx, 16); cx += __shfl_xor(cx, 32);
            if (g == 0) ctxl[w][li + 16 * nt] = cx + bv4[nt];
        }

        // ---- out-proj (same-wave LDS RAW: compiler inserts lgkmcnt wait) ----
        float o0 = 0.f, o1 = 0.f;
#pragma unroll
        for (int c2 = 0; c2 < 32; ++c2) {
            float2 cc = *(const float2*)&ctxl[w][2 * c2];
            uint2 W2 = WoP[c2 * 64 + l];
            o0 += cc.x * bflo(W2.x) + cc.y * bflo(W2.y);
            o1 += cc.x * bfhi(W2.x) + cc.y * bfhi(W2.y);
        }
        out[(size_t)bn * NH + l] = o0 + bo0;
        out[(size_t)bn * NH + 64 + l] = o1 + bo1;
    }
}

extern "C" void kernel_launch(void* const* d_in, const int* in_sizes, int n_in,
                              void* d_out, int out_size, void* d_ws, size_t ws_size,
                              hipStream_t stream) {
    const float* self_feat     = (const float*)d_in[0];
    const float* neighbor_feat = (const float*)d_in[1];
    const float* trust_mask    = (const float*)d_in[2];
    const float* eps           = (const float*)d_in[3];
    const float* pre_g  = (const float*)d_in[4];
    const float* pre_b  = (const float*)d_in[5];
    const float* W_mu   = (const float*)d_in[6];
    const float* b_mu   = (const float*)d_in[7];
    const float* W_lv   = (const float*)d_in[8];
    const float* b_lv   = (const float*)d_in[9];
    const float* post_g = (const float*)d_in[10];
    const float* post_b = (const float*)d_in[11];
    const float* W_q    = (const float*)d_in[12];
    const float* b_q    = (const float*)d_in[13];
    const float* W_k    = (const float*)d_in[14];
    const float* W_v    = (const float*)d_in[16];
    const float* b_v    = (const float*)d_in[17];
    const float* W_o    = (const float*)d_in[18];
    const float* b_o    = (const float*)d_in[19];
    float* out = (float*)d_out;

    // workspace: q bf16 (6.4MB) + z bf16 chunk buffer (up to 204.8MB)
    unsigned short* q_ws = (unsigned short*)d_ws;
    const size_t qbytes = (size_t)NB * NL * sizeof(unsigned short);
    unsigned short* z_ws = (unsigned short*)((char*)d_ws + qbytes);
    size_t zcap = (ws_size > qbytes) ? (ws_size - qbytes) : 0;
    long long chunk = (long long)(zcap / ((size_t)NK * NL * sizeof(unsigned short)));
    chunk &= ~7LL;                       // multiple of 8 (K_A nodes/block)
    if (chunk > NB) chunk = NB;
    if (chunk < 8) chunk = 8;            // (ws assumed >= ~7MB; round-5 ran with 19.2MB)

    hipLaunchKernelGGL(kl_zero_kernel, dim3(1), dim3(64), 0, stream, out);
    hipLaunchKernelGGL(q_kernel, dim3((NB + 31) / 32), dim3(256), 0, stream, self_feat, W_q, b_q, q_ws);

    for (int beg = 0; beg < NB; beg += (int)chunk) {
        int cnt = (NB - beg < (int)chunk) ? (NB - beg) : (int)chunk;
        hipLaunchKernelGGL(ka_kernel, dim3((cnt + 7) / 8), dim3(256), 0, stream,
                           neighbor_feat, eps, pre_g, pre_b,
                           W_mu, b_mu, W_lv, b_lv, post_g, post_b,
                           z_ws, out, beg, cnt);
        int gb = (cnt + 3) / 4; if (gb > 768) gb = 768;
        hipLaunchKernelGGL(kb_kernel, dim3(gb), dim3(256), 0, stream,
                           z_ws, trust_mask, q_ws,
                           W_k, W_v, b_v, W_o, b_o, out, beg, cnt);
    }
}